// Round 4
// baseline (602.306 us; speedup 1.0000x reference)
//
#include <hip/hip_runtime.h>
#include <hip/hip_bf16.h>
#include <stdint.h>

#define B_SZ   128
#define D_SZ   3072
#define N_SZ   20000
#define NPAD   20480   // 313*64 score tiles (20032) < NPAD; 40 drift K-chunks * 512

typedef __attribute__((ext_vector_type(8))) short        short8;
typedef __attribute__((ext_vector_type(4))) float        f32x4;
typedef __attribute__((ext_vector_type(4))) unsigned int uint4v;
typedef __attribute__((ext_vector_type(2))) unsigned int uint2v;

__device__ __forceinline__ unsigned short f2bf(float f) {
    unsigned u = __float_as_uint(f);
    u += 0x7FFFu + ((u >> 16) & 1u);   // round-to-nearest-even
    return (unsigned short)(u >> 16);
}
__device__ __forceinline__ float bf2f(unsigned short h) {
    return __uint_as_float(((unsigned)h) << 16);
}
// pack 2 fp32 -> 2 bf16 (RNE); a -> low 16 bits
__device__ __forceinline__ unsigned pk2bf(float a, float b) {
    __hip_bfloat162 h = __float22bfloat162_rn(make_float2(a, b));
    unsigned r;
    __builtin_memcpy(&r, &h, 4);
    return r;
}
// order-preserving float<->uint key for atomicMax over signed floats
__device__ __forceinline__ unsigned fkey_enc(float f) {
    unsigned b = __float_as_uint(f);
    return (b & 0x80000000u) ? ~b : (b | 0x80000000u);
}
__device__ __forceinline__ float fkey_dec(unsigned u) {
    return __uint_as_float((u & 0x80000000u) ? (u ^ 0x80000000u) : ~u);
}

// ---------------- zero the accumulator region of ws ----------------
__global__ __launch_bounds__(256) void zero_ws(float* __restrict__ p)
{
    p[blockIdx.x * 256 + threadIdx.x] = 0.f;   // exact grid
}

// ---------------- split x into bf16 hi/lo ----------------
__global__ __launch_bounds__(256) void prep_x(const float* __restrict__ x,
                                              unsigned short* __restrict__ xhi,
                                              unsigned short* __restrict__ xlo)
{
    int i = blockIdx.x * 256 + threadIdx.x;     // exactly 128*3072
    float v = x[i];
    unsigned short h = f2bf(v);
    xhi[i] = h;
    xlo[i] = f2bf(v - bf2f(h));
}

// ---------------- scores: XG[b][n] += partial x.g ; G2[n] += partial g2 -----
// grid = 313 n-tiles * 8 K-chunks = 2504 blocks. Tile M=128 x N=64, K-chunk 384.
// NO LDS, NO barriers: A (x hi/lo, L2-resident) and B (gt rows) fragments are
// k-contiguous in global memory exactly as MFMA wants them -> direct 16B loads
// per lane, distance-1 register prefetch. split-precision:
// acc = xhi*ghi + xhi*glo + xlo*ghi  (fp32-accurate dot)
__global__ __launch_bounds__(256, 3) void scores_kernel(
        const float* __restrict__ gt,
        const unsigned short* __restrict__ xhi,
        const unsigned short* __restrict__ xlo,
        float* __restrict__ XG,
        float* __restrict__ G2)
{
    const int tid   = threadIdx.x;
    const int kc    = blockIdx.x & 7;        // K-chunk (8 x 384)
    const int nt    = blockIdx.x >> 3;       // n-tile (313)
    const int nbase = nt * 64;
    const int kcb   = kc * 384;

    const int lane = tid & 63;
    const int wave = tid >> 6;
    const int mh = wave & 1;      // M half (64 rows)
    const int nh = wave >> 1;     // N half (32 cols)
    const int lm = lane & 15;
    const int qd = lane >> 4;

    // B-operand (gt) row pointers: lane(lm) -> n-row, qd -> k-offset
    int   nidx[2]; bool nval[2];
    const float* gp[2];
    #pragma unroll
    for (int ni = 0; ni < 2; ni++) {
        int n = nbase + nh * 32 + ni * 16 + lm;
        nval[ni] = (n < N_SZ);
        nidx[ni] = n;
        int ncl = nval[ni] ? n : (N_SZ - 1);
        gp[ni] = gt + (size_t)ncl * D_SZ + kcb + qd * 8;
    }
    // A-operand (x hi/lo) row pointers
    const unsigned short *xph[4], *xpl[4];
    #pragma unroll
    for (int mi = 0; mi < 4; mi++) {
        int m = mh * 64 + mi * 16 + lm;
        xph[mi] = xhi + (size_t)m * D_SZ + kcb + qd * 8;
        xpl[mi] = xlo + (size_t)m * D_SZ + kcb + qd * 8;
    }

    f32x4 acc[4][2];
    #pragma unroll
    for (int i = 0; i < 4; i++)
        #pragma unroll
        for (int j = 0; j < 2; j++)
            acc[i][j] = (f32x4){0.f, 0.f, 0.f, 0.f};
    float g2a[2] = {0.f, 0.f};

    // prologue: load k-step 0
    f32x4 gv[2][2];
    short8 ah[4], al[4];
    #pragma unroll
    for (int ni = 0; ni < 2; ni++) {
        gv[ni][0] = *(const f32x4*)(gp[ni]);
        gv[ni][1] = *(const f32x4*)(gp[ni] + 4);
    }
    #pragma unroll
    for (int mi = 0; mi < 4; mi++) {
        ah[mi] = *(const short8*)(xph[mi]);
        al[mi] = *(const short8*)(xpl[mi]);
    }

    #pragma unroll
    for (int k = 0; k < 12; k++) {
        // prefetch next step while computing this one (no barriers anywhere)
        f32x4 gvn[2][2];
        short8 ahn[4], aln[4];
        if (k < 11) {
            const int ko = (k + 1) * 32;
            #pragma unroll
            for (int ni = 0; ni < 2; ni++) {
                gvn[ni][0] = *(const f32x4*)(gp[ni] + ko);
                gvn[ni][1] = *(const f32x4*)(gp[ni] + ko + 4);
            }
            #pragma unroll
            for (int mi = 0; mi < 4; mi++) {
                ahn[mi] = *(const short8*)(xph[mi] + ko);
                aln[mi] = *(const short8*)(xpl[mi] + ko);
            }
        }

        // convert G fp32 -> bf16 hi/lo in registers, fused g2
        short8 bh[2], bl[2];
        #pragma unroll
        for (int ni = 0; ni < 2; ni++) {
            f32x4 v0 = gv[ni][0], v1 = gv[ni][1];
            unsigned u0 = pk2bf(v0[0], v0[1]);
            unsigned u1 = pk2bf(v0[2], v0[3]);
            unsigned u2 = pk2bf(v1[0], v1[1]);
            unsigned u3 = pk2bf(v1[2], v1[3]);
            float r0 = v0[0] - __uint_as_float(u0 << 16);
            float r1 = v0[1] - __uint_as_float(u0 & 0xFFFF0000u);
            float r2 = v0[2] - __uint_as_float(u1 << 16);
            float r3 = v0[3] - __uint_as_float(u1 & 0xFFFF0000u);
            float r4 = v1[0] - __uint_as_float(u2 << 16);
            float r5 = v1[1] - __uint_as_float(u2 & 0xFFFF0000u);
            float r6 = v1[2] - __uint_as_float(u3 << 16);
            float r7 = v1[3] - __uint_as_float(u3 & 0xFFFF0000u);
            unsigned w0 = pk2bf(r0, r1);
            unsigned w1 = pk2bf(r2, r3);
            unsigned w2 = pk2bf(r4, r5);
            unsigned w3 = pk2bf(r6, r7);
            uint4v hv = (uint4v){u0, u1, u2, u3};
            uint4v lv = (uint4v){w0, w1, w2, w3};
            __builtin_memcpy(&bh[ni], &hv, 16);
            __builtin_memcpy(&bl[ni], &lv, 16);
            if (mh == 0) {   // wave-uniform; count each g row once per block
                g2a[ni] += v0[0]*v0[0] + v0[1]*v0[1] + v0[2]*v0[2] + v0[3]*v0[3]
                         + v1[0]*v1[0] + v1[1]*v1[1] + v1[2]*v1[2] + v1[3]*v1[3];
            }
        }

        #pragma unroll
        for (int mi = 0; mi < 4; mi++) {
            #pragma unroll
            for (int ni = 0; ni < 2; ni++) {
                acc[mi][ni] = __builtin_amdgcn_mfma_f32_16x16x32_bf16(ah[mi], bh[ni], acc[mi][ni], 0, 0, 0);
                acc[mi][ni] = __builtin_amdgcn_mfma_f32_16x16x32_bf16(ah[mi], bl[ni], acc[mi][ni], 0, 0, 0);
                acc[mi][ni] = __builtin_amdgcn_mfma_f32_16x16x32_bf16(al[mi], bh[ni], acc[mi][ni], 0, 0, 0);
            }
        }

        if (k < 11) {
            #pragma unroll
            for (int ni = 0; ni < 2; ni++) { gv[ni][0] = gvn[ni][0]; gv[ni][1] = gvn[ni][1]; }
            #pragma unroll
            for (int mi = 0; mi < 4; mi++) { ah[mi] = ahn[mi]; al[mi] = aln[mi]; }
        }
    }

    // g2 partial: lanes lm, lm+16, lm+32, lm+48 hold qd-slices of row n
    #pragma unroll
    for (int ni = 0; ni < 2; ni++) {
        g2a[ni] += __shfl_xor(g2a[ni], 16);
        g2a[ni] += __shfl_xor(g2a[ni], 32);
        if (mh == 0 && qd == 0 && nval[ni]) atomicAdd(&G2[nidx[ni]], g2a[ni]);
    }

    // epilogue: C/D layout col=lane&15, row=qd*4+i ; raw partial -> atomicAdd
    #pragma unroll
    for (int mi = 0; mi < 4; mi++) {
        #pragma unroll
        for (int ni = 0; ni < 2; ni++) {
            int ng = nidx[ni];
            if (nval[ni]) {
                #pragma unroll
                for (int i = 0; i < 4; i++) {
                    int m = mh * 64 + mi * 16 + qd * 4 + i;
                    atomicAdd(&XG[(size_t)m * NPAD + ng], acc[mi][ni][i]);
                }
            }
        }
    }
}

// ---------------- maxk: row max of s = c1*xg - c2*g2, atomicMax per (b,chunk)
__global__ __launch_bounds__(256) void maxk(
        const float* __restrict__ XG, const float* __restrict__ G2,
        const float* __restrict__ tarr, unsigned* __restrict__ Mkey)
{
    const int b  = blockIdx.x >> 3;
    const int ch = blockIdx.x & 7;
    const int tid = threadIdx.x;
    float tt  = tarr[b] / 999.0f;
    float sig = 1.0f - tt;
    float inv = 1.0f / (sig * sig);
    float c1 = tt * inv, c2 = 0.5f * tt * tt * inv;
    const float* xg = XG + (size_t)b * NPAD;
    __shared__ float wred[4];

    float mx = -3.402823466e+38f;
    int n0 = ch * 2560;
    for (int n = n0 + tid; n < n0 + 2560; n += 256)
        if (n < N_SZ) mx = fmaxf(mx, c1 * xg[n] - c2 * G2[n]);
    #pragma unroll
    for (int o = 32; o > 0; o >>= 1) mx = fmaxf(mx, __shfl_xor(mx, o));
    if ((tid & 63) == 0) wred[tid >> 6] = mx;
    __syncthreads();
    if (tid == 0) {
        mx = fmaxf(fmaxf(wred[0], wred[1]), fmaxf(wred[2], wred[3]));
        atomicMax(&Mkey[b], fkey_enc(mx));
    }
}

// ---------------- expk: P = bf16(exp(s - m)), L[b] += partial sum ----------
__global__ __launch_bounds__(256) void expk(
        const float* __restrict__ XG, const float* __restrict__ G2,
        const float* __restrict__ tarr, const unsigned* __restrict__ Mkey,
        unsigned short* __restrict__ P, float* __restrict__ L)
{
    const int b  = blockIdx.x >> 3;
    const int ch = blockIdx.x & 7;
    const int tid = threadIdx.x;
    float tt  = tarr[b] / 999.0f;
    float sig = 1.0f - tt;
    float inv = 1.0f / (sig * sig);
    float c1 = tt * inv, c2 = 0.5f * tt * tt * inv;
    float m = fkey_dec(Mkey[b]);
    const float* xg = XG + (size_t)b * NPAD;
    unsigned short* prow = P + (size_t)b * NPAD;
    __shared__ float wred[4];

    float sum = 0.f;
    int n0 = ch * 2560;
    for (int n = n0 + tid; n < n0 + 2560; n += 256) {
        float p = 0.f;
        if (n < N_SZ) { p = expf(c1 * xg[n] - c2 * G2[n] - m); sum += p; }
        prow[n] = f2bf(p);            // pad region -> exact 0
    }
    #pragma unroll
    for (int o = 32; o > 0; o >>= 1) sum += __shfl_xor(sum, o);
    if ((tid & 63) == 0) wred[tid >> 6] = sum;
    __syncthreads();
    if (tid == 0) atomicAdd(&L[b], wred[0] + wred[1] + wred[2] + wred[3]);
}

// ---------------- drift: Dacc[b][d] += sum_k P[b][k]*gt_hi[k][d] -----------
// grid = 24 d-tiles * 40 K-chunks = 960 blocks; K-chunk 512 (16 steps of 32).
// P fragments read DIRECTLY from global (L2-resident, k-contiguous); only the
// k<->d transpose of gt goes through LDS. HBM-bound (~246 MB of gt).
__global__ __launch_bounds__(256) void drift_kernel(
        const float* __restrict__ gt,
        const unsigned short* __restrict__ P,
        float* __restrict__ Dacc)
{
    __shared__ __align__(16) unsigned short Gt[128 * 40];  // [d][k], row 80B (64B data + 16B pad)

    const int tid = threadIdx.x;
    const int nt = blockIdx.x % 24;
    const int kc = blockIdx.x / 24;
    const int dbase = nt * 128;

    const int lane = tid & 63;
    const int wave = tid >> 6;
    const int mh = wave & 1;
    const int dh = wave >> 1;
    const int lm = lane & 15;
    const int qd = lane >> 4;

    // G staging map: thread -> (d-group of 4 cols, k-group of 4 rows)
    const int dg = tid & 31;
    const int kq = tid >> 5;

    // P fragment pointers (direct global reads, 16B per lane)
    const unsigned short* pp[4];
    #pragma unroll
    for (int mi = 0; mi < 4; mi++)
        pp[mi] = P + (size_t)(mh * 64 + mi * 16 + lm) * NPAD + kc * 512 + qd * 8;

    f32x4 acc[4][4];
    #pragma unroll
    for (int i = 0; i < 4; i++)
        #pragma unroll
        for (int j = 0; j < 4; j++)
            acc[i][j] = (f32x4){0.f, 0.f, 0.f, 0.f};

    for (int s = 0; s < 16; s++) {
        int kb = kc * 512 + s * 32;
        // stage G transposed: global [k][d] fp32 -> LDS [d][k] bf16
        f32x4 row[4];
        #pragma unroll
        for (int i = 0; i < 4; i++) {
            int kg = kb + kq * 4 + i;
            if (kg > N_SZ - 1) kg = N_SZ - 1;   // clamp; P=0 there so product is 0
            row[i] = *(const f32x4*)(gt + (size_t)kg * D_SZ + dbase + dg * 4);
        }
        #pragma unroll
        for (int j = 0; j < 4; j++) {
            unsigned u01 = pk2bf(row[0][j], row[1][j]);
            unsigned u23 = pk2bf(row[2][j], row[3][j]);
            uint2v pk = (uint2v){u01, u23};
            __builtin_memcpy((char*)Gt + (size_t)(dg * 4 + j) * 80 + kq * 8, &pk, 8);
        }
        __syncthreads();

        short8 af[4], bf8[4];
        #pragma unroll
        for (int mi = 0; mi < 4; mi++)
            af[mi] = *(const short8*)(pp[mi] + s * 32);
        #pragma unroll
        for (int ni = 0; ni < 4; ni++)
            bf8[ni] = *(short8*)((char*)Gt + (size_t)(dh * 64 + ni * 16 + lm) * 80 + qd * 16);
        #pragma unroll
        for (int mi = 0; mi < 4; mi++)
            #pragma unroll
            for (int ni = 0; ni < 4; ni++)
                acc[mi][ni] = __builtin_amdgcn_mfma_f32_16x16x32_bf16(af[mi], bf8[ni], acc[mi][ni], 0, 0, 0);
        __syncthreads();
    }

    #pragma unroll
    for (int mi = 0; mi < 4; mi++)
        #pragma unroll
        for (int ni = 0; ni < 4; ni++) {
            int d = dbase + dh * 64 + ni * 16 + lm;
            #pragma unroll
            for (int i = 0; i < 4; i++) {
                int m = mh * 64 + mi * 16 + qd * 4 + i;
                atomicAdd(&Dacc[(size_t)m * D_SZ + d], acc[mi][ni][i]);
            }
        }
}

// ---------------- epilogue: out = (Dacc/L - x)/sig ----------------
__global__ __launch_bounds__(256) void epilogue_kernel(
        const float* __restrict__ Dacc, const float* __restrict__ L,
        const float* __restrict__ x, const float* __restrict__ tarr,
        float* __restrict__ out)
{
    int i = blockIdx.x * 256 + threadIdx.x;   // exactly 128*3072
    int b = i / D_SZ;
    float tt = tarr[b] / 999.0f;
    float sig = 1.0f - tt;
    out[i] = (Dacc[i] / L[b] - x[i]) / sig;
}

extern "C" void kernel_launch(void* const* d_in, const int* in_sizes, int n_in,
                              void* d_out, int out_size, void* d_ws, size_t ws_size,
                              hipStream_t stream)
{
    const float* xt = (const float*)d_in[0];   // [128,3,32,32]
    const float* t  = (const float*)d_in[1];   // [128]
    const float* gt = (const float*)d_in[2];   // [20000,3,32,32]
    float* out = (float*)d_out;

    char* ws = (char*)d_ws;
    // zero-initialized accumulator region (contiguous, 12141568 B = 3035392 f32):
    float*          XG  = (float*)         (ws + 0);          // 10485760 B [128][20480]
    float*          G2  = (float*)         (ws + 10485760);   //    81920 B [20480]
    float*          Dacc= (float*)         (ws + 10567680);   //  1572864 B [128][3072]
    unsigned*       Mkey= (unsigned*)      (ws + 12140544);   //      512 B [128]
    float*          L   = (float*)         (ws + 12141056);   //      512 B [128]
    // non-zeroed scratch:
    unsigned short* Xhi = (unsigned short*)(ws + 12141568);   //   786432 B
    unsigned short* Xlo = (unsigned short*)(ws + 12928000);   //   786432 B
    unsigned short* P   = (unsigned short*)(ws + 13714432);   //  5242880 B [128][20480]
    // total ~19.0 MB

    zero_ws       <<<11857, 256, 0, stream>>>((float*)ws);       // 3035392 f32
    prep_x        <<< 1536, 256, 0, stream>>>(xt, Xhi, Xlo);
    scores_kernel <<< 2504, 256, 0, stream>>>(gt, Xhi, Xlo, XG, G2);
    maxk          <<< 1024, 256, 0, stream>>>(XG, G2, t, Mkey);
    expk          <<< 1024, 256, 0, stream>>>(XG, G2, t, Mkey, P, L);
    drift_kernel  <<<  960, 256, 0, stream>>>(gt, P, Dacc);
    epilogue_kernel<<<1536, 256, 0, stream>>>(Dacc, L, xt, t, out);
}

// Round 5
// 486.353 us; speedup vs baseline: 1.2384x; 1.2384x over previous
//
#include <hip/hip_runtime.h>
#include <hip/hip_bf16.h>
#include <stdint.h>

#define B_SZ   128
#define D_SZ   3072
#define N_SZ   20000
#define NPAD   20480   // 313*64 score tiles (20032) < NPAD; 40 drift K-chunks * 512
#define BN     (B_SZ * NPAD)     // 2621440 elems
#define BD     (B_SZ * D_SZ)     // 393216 elems

typedef __attribute__((ext_vector_type(8))) short        short8;
typedef __attribute__((ext_vector_type(4))) float        f32x4;
typedef __attribute__((ext_vector_type(2))) unsigned int uint2v;

__device__ __forceinline__ unsigned short f2bf(float f) {
    unsigned u = __float_as_uint(f);
    u += 0x7FFFu + ((u >> 16) & 1u);   // round-to-nearest-even
    return (unsigned short)(u >> 16);
}
__device__ __forceinline__ float bf2f(unsigned short h) {
    return __uint_as_float(((unsigned)h) << 16);
}
// pack 2 fp32 -> 2 bf16 (RNE); a -> low 16 bits
__device__ __forceinline__ unsigned pk2bf(float a, float b) {
    __hip_bfloat162 h = __float22bfloat162_rn(make_float2(a, b));
    unsigned r;
    __builtin_memcpy(&r, &h, 4);
    return r;
}
// order-preserving float<->uint key for atomicMax over signed floats
__device__ __forceinline__ unsigned fkey_enc(float f) {
    unsigned b = __float_as_uint(f);
    return (b & 0x80000000u) ? ~b : (b | 0x80000000u);
}
__device__ __forceinline__ float fkey_dec(unsigned u) {
    return __uint_as_float((u & 0x80000000u) ? (u ^ 0x80000000u) : ~u);
}

__device__ __forceinline__ void gl_lds16(const void* g, void* l) {
    __builtin_amdgcn_global_load_lds(
        (const __attribute__((address_space(1))) void*)g,
        (__attribute__((address_space(3))) void*)l, 16, 0, 0);
}

// bank swizzle: 16B slot for (row r, k-quarter q) is q ^ ((r>>1)&3) -> 2-way
// aliasing only (free, m136); permutes within a 64B row so global coalescing
// of the staging loads is unchanged.
__device__ __forceinline__ int swz(int r, int q) { return q ^ ((r >> 1) & 3); }

// ---------------- zero G2 + Mkey + L (20736 floats, contiguous) ------------
__global__ __launch_bounds__(256) void zero_small(float* __restrict__ p)
{
    p[blockIdx.x * 256 + threadIdx.x] = 0.f;   // grid 81: 81*256 = 20736
}

// ---------------- split x into bf16 hi/lo ----------------
__global__ __launch_bounds__(256) void prep_x(const float* __restrict__ x,
                                              unsigned short* __restrict__ xhi,
                                              unsigned short* __restrict__ xlo)
{
    int i = blockIdx.x * 256 + threadIdx.x;     // exactly 128*3072
    float v = x[i];
    unsigned short h = f2bf(v);
    xhi[i] = h;
    xlo[i] = f2bf(v - bf2f(h));
}

// ---------------- scores: XG_part[kc][b][n] = partial x.g (plain stores) ----
// grid = 313 n-tiles * 8 K-chunks = 2504 blocks. Tile M=128 x N=64, K 384.
// NO atomics for the GEMM result (device-scope fp32 RMW was the R2 wall);
// G2 keeps 64 atomics/block (negligible). split-precision:
// acc = xhi*ghi + xhi*glo + xlo*ghi  (fp32-accurate dot)
__global__ __launch_bounds__(256) void scores_kernel(
        const float* __restrict__ gt,
        const unsigned short* __restrict__ xhi,
        const unsigned short* __restrict__ xlo,
        float* __restrict__ XG_part,
        float* __restrict__ G2)
{
    __shared__ __align__(16) unsigned short Xhi_t[128 * 32];
    __shared__ __align__(16) unsigned short Xlo_t[128 * 32];
    __shared__ __align__(16) unsigned short Ghi_t[64 * 32];
    __shared__ __align__(16) unsigned short Glo_t[64 * 32];

    const int tid   = threadIdx.x;
    const int kc    = blockIdx.x & 7;        // K-chunk (8 x 384)
    const int nt    = blockIdx.x >> 3;       // n-tile (313)
    const int nbase = nt * 64;
    const int kcb   = kc * 384;

    const int lane = tid & 63;
    const int wave = tid >> 6;
    const int mh = wave & 1;      // M half (64 rows)
    const int nh = wave >> 1;     // N half (32 cols)
    const int lm = lane & 15;
    const int qd = lane >> 4;

    // G staging map: thread -> (row gn of 64, k-quarter gq of 4 -> 8 elems)
    const int gn = tid >> 2;
    const int gq = tid & 3;
    const int ng0 = nbase + gn;              // unclamped (for guards)
    int grow = ng0 > N_SZ - 1 ? N_SZ - 1 : ng0;
    const float* gp0 = gt + (size_t)grow * D_SZ + kcb + gq * 8;
    const int gwr = gn * 32 + swz(gn, gq) * 8;   // swizzled LDS slot (elems)

    // X staging (global_load_lds, lane-order dest): lane's implicit LDS slot
    // is (r = o>>6, j = (o>>4)&3); fetch the global k-group j^f(r) so readers
    // can use the same swizzle.
    int xsrc[2], xdst[2];
    #pragma unroll
    for (int i = 0; i < 2; i++) {
        int o = (i * 256 + tid) * 16;
        int r = o >> 6;
        int j = (o >> 4) & 3;
        xdst[i] = o;
        xsrc[i] = r * D_SZ + kcb + swz(r, j) * 8;
    }

    float g2acc = 0.0f;

    f32x4 acc[4][2];
    #pragma unroll
    for (int i = 0; i < 4; i++)
        #pragma unroll
        for (int j = 0; j < 2; j++)
            acc[i][j] = (f32x4){0.f, 0.f, 0.f, 0.f};

    for (int k0 = 0; k0 < 384; k0 += 32) {
        // stage X hi/lo via async global->LDS
        #pragma unroll
        for (int i = 0; i < 2; i++) {
            gl_lds16(xhi + xsrc[i] + k0, (char*)Xhi_t + xdst[i]);
            gl_lds16(xlo + xsrc[i] + k0, (char*)Xlo_t + xdst[i]);
        }
        // stage G: fp32 load, hi/lo bf16 split, fused g2 accumulation
        f32x4 v0 = *(const f32x4*)(gp0 + k0);
        f32x4 v1 = *(const f32x4*)(gp0 + k0 + 4);
        short8 h8, l8;
        #pragma unroll
        for (int j = 0; j < 4; j++) {
            float a = v0[j], b = v1[j];
            unsigned short ha = f2bf(a), hb = f2bf(b);
            h8[j]     = (short)ha;  h8[j + 4] = (short)hb;
            l8[j]     = (short)f2bf(a - bf2f(ha));
            l8[j + 4] = (short)f2bf(b - bf2f(hb));
            g2acc += a * a + b * b;
        }
        *(short8*)&Ghi_t[gwr] = h8;
        *(short8*)&Glo_t[gwr] = l8;

        __syncthreads();

        short8 bhi[2], blo[2];
        #pragma unroll
        for (int ni = 0; ni < 2; ni++) {
            int r = nh * 32 + ni * 16 + lm;
            int sl = r * 32 + swz(r, qd) * 8;
            bhi[ni] = *(short8*)&Ghi_t[sl];
            blo[ni] = *(short8*)&Glo_t[sl];
        }
        #pragma unroll
        for (int mi = 0; mi < 4; mi++) {
            int r = mh * 64 + mi * 16 + lm;
            int sl = r * 32 + swz(r, qd) * 8;
            short8 ahi = *(short8*)&Xhi_t[sl];
            short8 alo = *(short8*)&Xlo_t[sl];
            #pragma unroll
            for (int ni = 0; ni < 2; ni++) {
                acc[mi][ni] = __builtin_amdgcn_mfma_f32_16x16x32_bf16(ahi, bhi[ni], acc[mi][ni], 0, 0, 0);
                acc[mi][ni] = __builtin_amdgcn_mfma_f32_16x16x32_bf16(ahi, blo[ni], acc[mi][ni], 0, 0, 0);
                acc[mi][ni] = __builtin_amdgcn_mfma_f32_16x16x32_bf16(alo, bhi[ni], acc[mi][ni], 0, 0, 0);
            }
        }
        __syncthreads();
    }

    // g2 partial: reduce over the 4 k-quarter threads of each row, one atomic
    g2acc += __shfl_xor(g2acc, 1);
    g2acc += __shfl_xor(g2acc, 2);
    if (gq == 0 && ng0 < N_SZ) atomicAdd(&G2[ng0], g2acc);

    // epilogue: C/D layout col=lane&15, row=qd*4+i ; plain store of partial
    float* XGp = XG_part + (size_t)kc * BN;
    #pragma unroll
    for (int mi = 0; mi < 4; mi++) {
        #pragma unroll
        for (int ni = 0; ni < 2; ni++) {
            int ncol = nh * 32 + ni * 16 + lm;
            int ng = nbase + ncol;
            if (ng < N_SZ) {
                #pragma unroll
                for (int i = 0; i < 4; i++) {
                    int m = mh * 64 + mi * 16 + qd * 4 + i;
                    XGp[(size_t)m * NPAD + ng] = acc[mi][ni][i];
                }
            }
        }
    }
}

// ---------------- sum8: XG = sum_kc XG_part[kc] ----------------
__global__ __launch_bounds__(256) void sum8(
        const float* __restrict__ XG_part, float* __restrict__ XG)
{
    int i = (blockIdx.x * 256 + threadIdx.x) * 4;   // grid 2560: covers BN
    f32x4 s = (f32x4){0.f, 0.f, 0.f, 0.f};
    #pragma unroll
    for (int kc = 0; kc < 8; kc++)
        s += *(const f32x4*)(XG_part + (size_t)kc * BN + i);
    *(f32x4*)(XG + i) = s;
}

// ---------------- maxk: row max of s = c1*xg - c2*g2, atomicMax per (b,chunk)
__global__ __launch_bounds__(256) void maxk(
        const float* __restrict__ XG, const float* __restrict__ G2,
        const float* __restrict__ tarr, unsigned* __restrict__ Mkey)
{
    const int b  = blockIdx.x >> 3;
    const int ch = blockIdx.x & 7;
    const int tid = threadIdx.x;
    float tt  = tarr[b] / 999.0f;
    float sig = 1.0f - tt;
    float inv = 1.0f / (sig * sig);
    float c1 = tt * inv, c2 = 0.5f * tt * tt * inv;
    const float* xg = XG + (size_t)b * NPAD;
    __shared__ float wred[4];

    float mx = -3.402823466e+38f;
    int n0 = ch * 2560;
    for (int n = n0 + tid; n < n0 + 2560; n += 256)
        if (n < N_SZ) mx = fmaxf(mx, c1 * xg[n] - c2 * G2[n]);
    #pragma unroll
    for (int o = 32; o > 0; o >>= 1) mx = fmaxf(mx, __shfl_xor(mx, o));
    if ((tid & 63) == 0) wred[tid >> 6] = mx;
    __syncthreads();
    if (tid == 0) {
        mx = fmaxf(fmaxf(wred[0], wred[1]), fmaxf(wred[2], wred[3]));
        atomicMax(&Mkey[b], fkey_enc(mx));
    }
}

// ---------------- expk: P = bf16(exp(s - m)), L[b] += partial sum ----------
__global__ __launch_bounds__(256) void expk(
        const float* __restrict__ XG, const float* __restrict__ G2,
        const float* __restrict__ tarr, const unsigned* __restrict__ Mkey,
        unsigned short* __restrict__ P, float* __restrict__ L)
{
    const int b  = blockIdx.x >> 3;
    const int ch = blockIdx.x & 7;
    const int tid = threadIdx.x;
    float tt  = tarr[b] / 999.0f;
    float sig = 1.0f - tt;
    float inv = 1.0f / (sig * sig);
    float c1 = tt * inv, c2 = 0.5f * tt * tt * inv;
    float m = fkey_dec(Mkey[b]);
    const float* xg = XG + (size_t)b * NPAD;
    unsigned short* prow = P + (size_t)b * NPAD;
    __shared__ float wred[4];

    float sum = 0.f;
    int n0 = ch * 2560;
    for (int n = n0 + tid; n < n0 + 2560; n += 256) {
        float p = 0.f;
        if (n < N_SZ) { p = expf(c1 * xg[n] - c2 * G2[n] - m); sum += p; }
        prow[n] = f2bf(p);            // pad region -> exact 0
    }
    #pragma unroll
    for (int o = 32; o > 0; o >>= 1) sum += __shfl_xor(sum, o);
    if ((tid & 63) == 0) wred[tid >> 6] = sum;
    __syncthreads();
    if (tid == 0) atomicAdd(&L[b], wred[0] + wred[1] + wred[2] + wred[3]);
}

// ---------------- drift: Dacc_part[kc][b][d] = partial P.gt (plain stores) -
// grid = 24 d-tiles * 40 K-chunks = 960 blocks; K-chunk 512 (16 steps of 32).
__global__ __launch_bounds__(256) void drift_kernel(
        const float* __restrict__ gt,
        const unsigned short* __restrict__ P,
        float* __restrict__ Dacc_part)
{
    __shared__ __align__(16) unsigned short Pt[128 * 32];
    __shared__ __align__(16) unsigned short Gt[128 * 40];  // [d][k], 80B rows (64B + 16B pad)

    const int tid = threadIdx.x;
    const int nt = blockIdx.x % 24;
    const int kc = blockIdx.x / 24;
    const int dbase = nt * 128;

    const int lane = tid & 63;
    const int wave = tid >> 6;
    const int mh = wave & 1;
    const int dh = wave >> 1;
    const int lm = lane & 15;
    const int qd = lane >> 4;

    // G staging map: thread -> (d-group of 4 cols, k-group of 4 rows)
    const int dg = tid & 31;
    const int kq = tid >> 5;

    // P staging (global_load_lds, swizzled source like scores' X)
    int psrc[2], pdst[2];
    #pragma unroll
    for (int i = 0; i < 2; i++) {
        int o = (i * 256 + tid) * 16;
        int r = o >> 6;
        int j = (o >> 4) & 3;
        pdst[i] = o;
        psrc[i] = r * NPAD + kc * 512 + swz(r, j) * 8;
    }

    f32x4 acc[4][4];
    #pragma unroll
    for (int i = 0; i < 4; i++)
        #pragma unroll
        for (int j = 0; j < 4; j++)
            acc[i][j] = (f32x4){0.f, 0.f, 0.f, 0.f};

    for (int s = 0; s < 16; s++) {
        int kb = kc * 512 + s * 32;
        // stage P tile (128 x 32 bf16) direct to LDS
        #pragma unroll
        for (int i = 0; i < 2; i++)
            gl_lds16(P + psrc[i] + s * 32, (char*)Pt + pdst[i]);
        // stage G transposed: global [k][d] fp32 -> LDS [d][k] bf16
        f32x4 row[4];
        #pragma unroll
        for (int i = 0; i < 4; i++) {
            int kg = kb + kq * 4 + i;
            if (kg > N_SZ - 1) kg = N_SZ - 1;   // clamp; P=0 there so product is 0
            row[i] = *(const f32x4*)(gt + (size_t)kg * D_SZ + dbase + dg * 4);
        }
        #pragma unroll
        for (int j = 0; j < 4; j++) {
            unsigned u01 = pk2bf(row[0][j], row[1][j]);
            unsigned u23 = pk2bf(row[2][j], row[3][j]);
            uint2v pk = (uint2v){u01, u23};
            __builtin_memcpy((char*)Gt + (size_t)(dg * 4 + j) * 80 + kq * 8, &pk, 8);
        }
        __syncthreads();

        short8 af[4], bf8[4];
        #pragma unroll
        for (int mi = 0; mi < 4; mi++) {
            int r = mh * 64 + mi * 16 + lm;
            af[mi] = *(short8*)&Pt[r * 32 + swz(r, qd) * 8];
        }
        #pragma unroll
        for (int ni = 0; ni < 4; ni++)
            bf8[ni] = *(short8*)((char*)Gt + (size_t)(dh * 64 + ni * 16 + lm) * 80 + qd * 16);
        #pragma unroll
        for (int mi = 0; mi < 4; mi++)
            #pragma unroll
            for (int ni = 0; ni < 4; ni++)
                acc[mi][ni] = __builtin_amdgcn_mfma_f32_16x16x32_bf16(af[mi], bf8[ni], acc[mi][ni], 0, 0, 0);
        __syncthreads();
    }

    float* Dp = Dacc_part + (size_t)kc * BD;
    #pragma unroll
    for (int mi = 0; mi < 4; mi++)
        #pragma unroll
        for (int ni = 0; ni < 4; ni++) {
            int d = dbase + dh * 64 + ni * 16 + lm;
            #pragma unroll
            for (int i = 0; i < 4; i++) {
                int m = mh * 64 + mi * 16 + qd * 4 + i;
                Dp[(size_t)m * D_SZ + d] = acc[mi][ni][i];
            }
        }
}

// ---------------- epilogue: out = (sum_kc Dacc_part / L - x)/sig ----------
__global__ __launch_bounds__(256) void epilogue_kernel(
        const float* __restrict__ Dacc_part, const float* __restrict__ L,
        const float* __restrict__ x, const float* __restrict__ tarr,
        float* __restrict__ out)
{
    int i = (blockIdx.x * 256 + threadIdx.x) * 4;   // grid 384: covers BD
    int b = i / D_SZ;
    f32x4 s = (f32x4){0.f, 0.f, 0.f, 0.f};
    #pragma unroll
    for (int kc = 0; kc < 40; kc++)
        s += *(const f32x4*)(Dacc_part + (size_t)kc * BD + i);
    float tt = tarr[b] / 999.0f;
    float sig = 1.0f - tt;
    float invL = 1.0f / L[b];
    f32x4 xv = *(const f32x4*)(x + i);
    f32x4 o;
    #pragma unroll
    for (int j = 0; j < 4; j++) o[j] = (s[j] * invL - xv[j]) / sig;
    *(f32x4*)(out + i) = o;
}

extern "C" void kernel_launch(void* const* d_in, const int* in_sizes, int n_in,
                              void* d_out, int out_size, void* d_ws, size_t ws_size,
                              hipStream_t stream)
{
    const float* xt = (const float*)d_in[0];   // [128,3,32,32]
    const float* t  = (const float*)d_in[1];   // [128]
    const float* gt = (const float*)d_in[2];   // [20000,3,32,32]
    float* out = (float*)d_out;

    char* ws = (char*)d_ws;
    float*          XG_part  = (float*)(ws + 0);            // 8*BN*4   = 83886080
    float*          XG       = (float*)(ws + 83886080);     // BN*4     = 10485760
    float*          Dacc_part= (float*)(ws + 94371840);     // 40*BD*4  = 62914560
    float*          G2       = (float*)(ws + 157286400);    // 81920  } zeroed
    unsigned*       Mkey     = (unsigned*)(ws + 157368320); //   512  } contiguous
    float*          L        = (float*)(ws + 157368832);    //   512  } 20736 f32
    unsigned short* Xhi      = (unsigned short*)(ws + 157369344); // 786432
    unsigned short* Xlo      = (unsigned short*)(ws + 158155776); // 786432
    unsigned short* P        = (unsigned short*)(ws + 158942208); // 5242880
    // total ~164 MB (< ws poison size 983 MB)

    zero_small    <<<   81, 256, 0, stream>>>(G2);           // G2+Mkey+L
    prep_x        <<< 1536, 256, 0, stream>>>(xt, Xhi, Xlo);
    scores_kernel <<< 2504, 256, 0, stream>>>(gt, Xhi, Xlo, XG_part, G2);
    sum8          <<< 2560, 256, 0, stream>>>(XG_part, XG);
    maxk          <<< 1024, 256, 0, stream>>>(XG, G2, t, Mkey);
    expk          <<< 1024, 256, 0, stream>>>(XG, G2, t, Mkey, P, L);
    drift_kernel  <<<  960, 256, 0, stream>>>(gt, P, Dacc_part);
    epilogue_kernel<<< 384, 256, 0, stream>>>(Dacc_part, L, xt, t, out);
}